// Round 1
// baseline (1249.214 us; speedup 1.0000x reference)
//
#include <hip/hip_runtime.h>
#include <hip/hip_bf16.h>
#include <math.h>

#define T_TOKENS 4096
#define DMODEL 1024
#define DFF 4096
#define NEXP 24
#define PADK 40           // 32 + 8 pad (2-way LDS conflict = free)
#define CAP_TILES 16      // up to 2048 tokens/expert (expected max ~450)

typedef __attribute__((ext_vector_type(8))) short bf16x8;
typedef __attribute__((ext_vector_type(4))) float f32x4;
typedef __attribute__((ext_vector_type(8))) unsigned short us8;

static __device__ __forceinline__ unsigned short f2bf(float f) {
    union { float f; unsigned u; } v; v.f = f;
    unsigned r = v.u + 0x7fffu + ((v.u >> 16) & 1u);
    return (unsigned short)(r >> 16);
}

// ---------------- gating: 1 wave per token ----------------
__global__ __launch_bounds__(256) void k_gate(
    const float* __restrict__ x, const float* __restrict__ gw,
    const float* __restrict__ gb, int* __restrict__ topk_e,
    float* __restrict__ topk_g, int* __restrict__ counts)
{
    int wave = threadIdx.x >> 6, lane = threadIdx.x & 63;
    int t = blockIdx.x * 4 + wave;
    const float* xp = x + (size_t)t * DMODEL + lane * 16;
    float xr[16];
    #pragma unroll
    for (int i = 0; i < 4; i++) {
        float4 v = ((const float4*)xp)[i];
        xr[4*i+0]=v.x; xr[4*i+1]=v.y; xr[4*i+2]=v.z; xr[4*i+3]=v.w;
    }
    float v0 = -1e30f, v1 = -1e30f; int i0 = 0, i1 = 0;
    for (int e = 0; e < NEXP; e++) {
        float s = 0.f;
        #pragma unroll
        for (int i = 0; i < 16; i++)
            s += xr[i] * gw[(size_t)(lane*16 + i) * NEXP + e];
        #pragma unroll
        for (int off = 32; off; off >>= 1) s += __shfl_xor(s, off);
        s += gb[e];
        if (s > v0) { v1 = v0; i1 = i0; v0 = s; i0 = e; }
        else if (s > v1) { v1 = s; i1 = e; }
    }
    if (lane == 0) {
        float e1 = expf(v1 - v0);
        float g0 = 1.f / (1.f + e1);
        float g1 = e1 / (1.f + e1);
        topk_e[t*2] = i0; topk_e[t*2+1] = i1;
        topk_g[t*2] = g0; topk_g[t*2+1] = g1;
        atomicAdd(&counts[i0], 1);
        atomicAdd(&counts[i1], 1);
    }
}

__global__ void k_scan(const int* __restrict__ counts, int* __restrict__ offsets) {
    if (threadIdx.x == 0) {
        int run = 0;
        for (int e = 0; e < NEXP; e++) { offsets[e] = run; run += counts[e]; }
        offsets[NEXP] = run;
    }
}

__global__ __launch_bounds__(256) void k_assign(
    const int* __restrict__ topk_e, const float* __restrict__ topk_g,
    const int* __restrict__ offsets, int* __restrict__ counts2,
    int* __restrict__ slot_token, float* __restrict__ slot_gate)
{
    int idx = blockIdx.x * 256 + threadIdx.x;
    if (idx >= T_TOKENS * 2) return;
    int e = topk_e[idx];
    int pos = offsets[e] + atomicAdd(&counts2[e], 1);
    slot_token[pos] = idx >> 1;
    slot_gate[pos] = topk_g[idx];
}

// ---------------- GEMM1: h = gelu(x[tok] @ w1[e] + b1[e]) ----------------
__global__ __launch_bounds__(256) void k_ffn1(
    const float* __restrict__ x, const float* __restrict__ w1,
    const float* __restrict__ b1, const int* __restrict__ offsets,
    const int* __restrict__ slot_token, unsigned short* __restrict__ hbuf)
{
    int e = blockIdx.z;
    int base = offsets[e], ne = offsets[e+1] - base;
    int mt = blockIdx.y;
    if (mt * 128 >= ne) return;
    int n0 = blockIdx.x * 128;
    int slotbase = base + mt * 128;

    __shared__ unsigned short As[128][PADK];
    __shared__ unsigned short Bs[128][PADK];   // transposed: Bs[n][k]
    __shared__ int tok[128];

    int tid = threadIdx.x;
    if (tid < 128) {
        int m = mt*128 + tid;
        tok[tid] = (m < ne) ? slot_token[slotbase + tid] : 0;
    }
    __syncthreads();

    int lane = tid & 63, wv = tid >> 6;
    int wm = (wv >> 1) * 64, wn = (wv & 1) * 64;
    int lrow = lane & 15, lkg = lane >> 4;

    f32x4 acc[4][4];
    #pragma unroll
    for (int i = 0; i < 4; i++)
      #pragma unroll
      for (int j = 0; j < 4; j++)
        acc[i][j] = (f32x4){0.f, 0.f, 0.f, 0.f};

    const float* w1e = w1 + (size_t)e * DMODEL * DFF;

    for (int k0 = 0; k0 < DMODEL; k0 += 32) {
        // A: 128x32 fp32 -> bf16 LDS
        #pragma unroll
        for (int i = 0; i < 4; i++) {
            int idx = tid + 256*i;
            int r = idx >> 3, c4 = (idx & 7) * 4;
            float4 v = *(const float4*)(x + (size_t)tok[r]*DMODEL + k0 + c4);
            As[r][c4+0] = f2bf(v.x); As[r][c4+1] = f2bf(v.y);
            As[r][c4+2] = f2bf(v.z); As[r][c4+3] = f2bf(v.w);
        }
        // B: 32x128 fp32, transpose into Bs[n][k]
        #pragma unroll
        for (int i = 0; i < 4; i++) {
            int idx = tid + 256*i;
            int kr = idx >> 5, c4 = (idx & 31) * 4;
            float4 v = *(const float4*)(w1e + (size_t)(k0+kr)*DFF + n0 + c4);
            Bs[c4+0][kr] = f2bf(v.x);
            Bs[c4+1][kr] = f2bf(v.y);
            Bs[c4+2][kr] = f2bf(v.z);
            Bs[c4+3][kr] = f2bf(v.w);
        }
        __syncthreads();
        bf16x8 a[4], b[4];
        #pragma unroll
        for (int i = 0; i < 4; i++)
            a[i] = *(const bf16x8*)&As[wm + i*16 + lrow][lkg*8];
        #pragma unroll
        for (int i = 0; i < 4; i++)
            b[i] = *(const bf16x8*)&Bs[wn + i*16 + lrow][lkg*8];
        #pragma unroll
        for (int mi = 0; mi < 4; mi++)
          #pragma unroll
          for (int ni = 0; ni < 4; ni++)
            acc[mi][ni] = __builtin_amdgcn_mfma_f32_16x16x32_bf16(a[mi], b[ni], acc[mi][ni], 0, 0, 0);
        __syncthreads();
    }

    #pragma unroll
    for (int mi = 0; mi < 4; mi++) {
        #pragma unroll
        for (int ni = 0; ni < 4; ni++) {
            int n = n0 + wn + ni*16 + lrow;
            float bias = b1[e*DFF + n];
            #pragma unroll
            for (int r = 0; r < 4; r++) {
                int ml = wm + mi*16 + lkg*4 + r;
                if (mt*128 + ml < ne) {
                    float hv = acc[mi][ni][r] + bias;
                    hv = 0.5f * hv * (1.f + erff(hv * 0.70710678118f));
                    hbuf[(size_t)(slotbase + ml) * DFF + n] = f2bf(hv);
                }
            }
        }
    }
}

// ---------------- GEMM2: out[tok] += g * (h @ w2[e] + b2[e]) ----------------
__global__ __launch_bounds__(256) void k_ffn2(
    const unsigned short* __restrict__ hbuf, const float* __restrict__ w2,
    const float* __restrict__ b2, const int* __restrict__ offsets,
    const int* __restrict__ slot_token, const float* __restrict__ slot_gate,
    float* __restrict__ out)
{
    int e = blockIdx.z;
    int base = offsets[e], ne = offsets[e+1] - base;
    int mt = blockIdx.y;
    if (mt * 128 >= ne) return;
    int n0 = blockIdx.x * 128;
    int slotbase = base + mt * 128;

    __shared__ unsigned short As[128][PADK];
    __shared__ unsigned short Bs[128][PADK];
    __shared__ int tok[128];
    __shared__ float gat[128];

    int tid = threadIdx.x;
    if (tid < 128) {
        int m = mt*128 + tid;
        tok[tid] = (m < ne) ? slot_token[slotbase + tid] : 0;
        gat[tid] = (m < ne) ? slot_gate[slotbase + tid] : 0.f;
    }
    __syncthreads();

    int lane = tid & 63, wv = tid >> 6;
    int wm = (wv >> 1) * 64, wn = (wv & 1) * 64;
    int lrow = lane & 15, lkg = lane >> 4;

    f32x4 acc[4][4];
    #pragma unroll
    for (int i = 0; i < 4; i++)
      #pragma unroll
      for (int j = 0; j < 4; j++)
        acc[i][j] = (f32x4){0.f, 0.f, 0.f, 0.f};

    const float* w2e = w2 + (size_t)e * DFF * DMODEL;

    for (int k0 = 0; k0 < DFF; k0 += 32) {
        // A: 128x32 bf16 straight copy from hbuf (padded rows: garbage ok)
        #pragma unroll
        for (int i = 0; i < 2; i++) {
            int ch = tid + 256*i;
            int r = ch >> 2, q = (ch & 3) * 8;
            us8 v = *(const us8*)(hbuf + (size_t)(slotbase + r)*DFF + k0 + q);
            *(us8*)&As[r][q] = v;
        }
        // B: 32x128 fp32, transpose into Bs[n][k]
        #pragma unroll
        for (int i = 0; i < 4; i++) {
            int idx = tid + 256*i;
            int kr = idx >> 5, c4 = (idx & 31) * 4;
            float4 v = *(const float4*)(w2e + (size_t)(k0+kr)*DMODEL + n0 + c4);
            Bs[c4+0][kr] = f2bf(v.x);
            Bs[c4+1][kr] = f2bf(v.y);
            Bs[c4+2][kr] = f2bf(v.z);
            Bs[c4+3][kr] = f2bf(v.w);
        }
        __syncthreads();
        bf16x8 a[4], b[4];
        #pragma unroll
        for (int i = 0; i < 4; i++)
            a[i] = *(const bf16x8*)&As[wm + i*16 + lrow][lkg*8];
        #pragma unroll
        for (int i = 0; i < 4; i++)
            b[i] = *(const bf16x8*)&Bs[wn + i*16 + lrow][lkg*8];
        #pragma unroll
        for (int mi = 0; mi < 4; mi++)
          #pragma unroll
          for (int ni = 0; ni < 4; ni++)
            acc[mi][ni] = __builtin_amdgcn_mfma_f32_16x16x32_bf16(a[mi], b[ni], acc[mi][ni], 0, 0, 0);
        __syncthreads();
    }

    #pragma unroll
    for (int mi = 0; mi < 4; mi++) {
        #pragma unroll
        for (int ni = 0; ni < 4; ni++) {
            int n = n0 + wn + ni*16 + lrow;
            float bias = b2[e*DMODEL + n];
            #pragma unroll
            for (int r = 0; r < 4; r++) {
                int ml = wm + mi*16 + lkg*4 + r;
                if (mt*128 + ml < ne) {
                    float yv = acc[mi][ni][r] + bias;
                    atomicAdd(&out[(size_t)tok[ml] * DMODEL + n], gat[ml] * yv);
                }
            }
        }
    }
}

extern "C" void kernel_launch(void* const* d_in, const int* in_sizes, int n_in,
                              void* d_out, int out_size, void* d_ws, size_t ws_size,
                              hipStream_t stream) {
    const float* x  = (const float*)d_in[0];
    const float* gw = (const float*)d_in[1];
    const float* gb = (const float*)d_in[2];
    const float* w1 = (const float*)d_in[3];
    const float* b1 = (const float*)d_in[4];
    const float* w2 = (const float*)d_in[5];
    const float* b2 = (const float*)d_in[6];
    float* out = (float*)d_out;
    char* ws = (char*)d_ws;

    int*   counts     = (int*)(ws + 0);        // 24
    int*   counts2    = (int*)(ws + 128);      // 24
    int*   offsets    = (int*)(ws + 256);      // 25
    int*   topk_e     = (int*)(ws + 512);      // 8192
    float* topk_g     = (float*)(ws + 512 + 32768);
    int*   slot_token = (int*)(ws + 512 + 65536);            // 8320 (padded)
    float* slot_gate  = (float*)(ws + 512 + 65536 + 33280);  // 8320 (padded)
    unsigned short* hbuf = (unsigned short*)(ws + 132608);   // 8320 x 4096 bf16

    hipMemsetAsync(ws, 0, 512, stream);
    hipMemsetAsync(out, 0, (size_t)T_TOKENS * DMODEL * sizeof(float), stream);

    k_gate<<<T_TOKENS/4, 256, 0, stream>>>(x, gw, gb, topk_e, topk_g, counts);
    k_scan<<<1, 64, 0, stream>>>(counts, offsets);
    k_assign<<<(T_TOKENS*2)/256, 256, 0, stream>>>(topk_e, topk_g, offsets, counts2,
                                                   slot_token, slot_gate);
    dim3 g1(DFF/128, CAP_TILES, NEXP);
    k_ffn1<<<g1, 256, 0, stream>>>(x, w1, b1, offsets, slot_token, hbuf);
    dim3 g2(DMODEL/128, CAP_TILES, NEXP);
    k_ffn2<<<g2, 256, 0, stream>>>(hbuf, w2, b2, offsets, slot_token, slot_gate, out);
}

// Round 2
// 903.097 us; speedup vs baseline: 1.3833x; 1.3833x over previous
//
#include <hip/hip_runtime.h>
#include <hip/hip_bf16.h>
#include <math.h>

#define T_TOKENS 4096
#define DMODEL 1024
#define DFF 4096
#define NEXP 24
#define NSLOTS 8192
#define SLOTS_PAD 8320

typedef __attribute__((ext_vector_type(8))) short bf16x8;
typedef __attribute__((ext_vector_type(4))) float f32x4;
typedef __attribute__((ext_vector_type(8))) unsigned short us8;

static __device__ __forceinline__ unsigned short f2bf(float f) {
    union { float f; unsigned u; } v; v.f = f;
    unsigned r = v.u + 0x7fffu + ((v.u >> 16) & 1u);
    return (unsigned short)(r >> 16);
}

typedef const __attribute__((address_space(1))) void gvoid_t;
typedef __attribute__((address_space(3))) void lvoid_t;
static __device__ __forceinline__ void gl_lds16(const void* g, void* l) {
    __builtin_amdgcn_global_load_lds((gvoid_t*)g, (lvoid_t*)l, 16, 0, 0);
}

// ---------------- gating: 1 wave per token (fp32 exact, unchanged) ----------------
__global__ __launch_bounds__(256) void k_gate(
    const float* __restrict__ x, const float* __restrict__ gw,
    const float* __restrict__ gb, int* __restrict__ topk_e,
    float* __restrict__ topk_g, int* __restrict__ counts)
{
    int wave = threadIdx.x >> 6, lane = threadIdx.x & 63;
    int t = blockIdx.x * 4 + wave;
    const float* xp = x + (size_t)t * DMODEL + lane * 16;
    float xr[16];
    #pragma unroll
    for (int i = 0; i < 4; i++) {
        float4 v = ((const float4*)xp)[i];
        xr[4*i+0]=v.x; xr[4*i+1]=v.y; xr[4*i+2]=v.z; xr[4*i+3]=v.w;
    }
    float v0 = -1e30f, v1 = -1e30f; int i0 = 0, i1 = 0;
    for (int e = 0; e < NEXP; e++) {
        float s = 0.f;
        #pragma unroll
        for (int i = 0; i < 16; i++)
            s += xr[i] * gw[(size_t)(lane*16 + i) * NEXP + e];
        #pragma unroll
        for (int off = 32; off; off >>= 1) s += __shfl_xor(s, off);
        s += gb[e];
        if (s > v0) { v1 = v0; i1 = i0; v0 = s; i0 = e; }
        else if (s > v1) { v1 = s; i1 = e; }
    }
    if (lane == 0) {
        float e1 = expf(v1 - v0);
        float g0 = 1.f / (1.f + e1);
        float g1 = e1 / (1.f + e1);
        topk_e[t*2] = i0; topk_e[t*2+1] = i1;
        topk_g[t*2] = g0; topk_g[t*2+1] = g1;
        atomicAdd(&counts[i0], 1);
        atomicAdd(&counts[i1], 1);
    }
}

__global__ void k_scan(const int* __restrict__ counts, int* __restrict__ offsets) {
    if (threadIdx.x == 0) {
        int run = 0;
        for (int e = 0; e < NEXP; e++) { offsets[e] = run; run += counts[e]; }
        offsets[NEXP] = run;
    }
}

__global__ __launch_bounds__(256) void k_assign(
    const int* __restrict__ topk_e, const float* __restrict__ topk_g,
    const int* __restrict__ offsets, int* __restrict__ counts2,
    int* __restrict__ slot_token, float* __restrict__ slot_gate,
    int* __restrict__ slot_of)
{
    int idx = blockIdx.x * 256 + threadIdx.x;
    if (idx >= NSLOTS) return;
    int e = topk_e[idx];
    int pos = offsets[e] + atomicAdd(&counts2[e], 1);
    slot_token[pos] = idx >> 1;
    slot_gate[pos] = topk_g[idx];
    slot_of[idx] = pos;
}

// ---------------- gather x -> xg[slot][DMODEL] bf16 ----------------
__global__ __launch_bounds__(256) void k_xgather(
    const float* __restrict__ x, const int* __restrict__ slot_token,
    unsigned short* __restrict__ xg)
{
    int idx = blockIdx.x * 256 + threadIdx.x;     // 8192*128 threads
    int slot = idx >> 7, c8 = (idx & 127) * 8;
    int tok = slot_token[slot];
    const float4* p = (const float4*)(x + (size_t)tok * DMODEL + c8);
    float4 v0 = p[0], v1 = p[1];
    us8 o;
    o[0]=f2bf(v0.x); o[1]=f2bf(v0.y); o[2]=f2bf(v0.z); o[3]=f2bf(v0.w);
    o[4]=f2bf(v1.x); o[5]=f2bf(v1.y); o[6]=f2bf(v1.z); o[7]=f2bf(v1.w);
    *(us8*)(xg + (size_t)slot * DMODEL + c8) = o;
}

// ---------------- weight convert+transpose: in [E][R][C] f32 -> out [E][C][R] bf16 ----
__global__ __launch_bounds__(256) void k_wt(
    const float* __restrict__ in, unsigned short* __restrict__ out, int R, int C)
{
    __shared__ unsigned short Lt[64][66];
    int e = blockIdx.z;
    int c0 = blockIdx.x * 64, r0 = blockIdx.y * 64;
    const float* ip = in + (size_t)e * R * C;
    unsigned short* op = out + (size_t)e * R * C;
    int tid = threadIdx.x;
    #pragma unroll
    for (int i = 0; i < 4; i++) {
        int idx = tid + 256*i;
        int r = idx >> 4, c4 = (idx & 15) * 4;
        float4 v = *(const float4*)(ip + (size_t)(r0+r)*C + c0 + c4);
        unsigned lo = (unsigned)f2bf(v.x) | ((unsigned)f2bf(v.y) << 16);
        unsigned hi = (unsigned)f2bf(v.z) | ((unsigned)f2bf(v.w) << 16);
        *(unsigned*)&Lt[r][c4]   = lo;
        *(unsigned*)&Lt[r][c4+2] = hi;
    }
    __syncthreads();
    #pragma unroll
    for (int j = 0; j < 2; j++) {
        int idx = tid + 256*j;
        int c = idx >> 3, r8 = (idx & 7) * 8;
        us8 o;
        #pragma unroll
        for (int k = 0; k < 8; k++) o[k] = Lt[r8+k][c];
        *(us8*)(op + (size_t)(c0+c)*R + r0 + r8) = o;
    }
}

// ---------------- GEMM1: h = gelu(xg @ w1t^T + b1), m97 structure ----------------
__global__ __launch_bounds__(256) void k_ffn1(
    const unsigned short* __restrict__ xg, const unsigned short* __restrict__ w1t,
    const float* __restrict__ b1, const int* __restrict__ offsets,
    unsigned short* __restrict__ hbuf)
{
    int e = blockIdx.z;
    int base = offsets[e], ne = offsets[e+1] - base;
    int mt = blockIdx.y;
    if (mt * 128 >= ne) return;
    int n0 = blockIdx.x * 128;
    int slotbase = base + mt * 128;

    __shared__ unsigned short As[128*32];
    __shared__ unsigned short Bs[128*32];

    int tid = threadIdx.x, l = tid & 63, wv = tid >> 6;
    int wm = (wv >> 1) * 64, wn = (wv & 1) * 64;
    int lrow = l & 15, lkg = l >> 4;

    f32x4 acc[4][4];
    #pragma unroll
    for (int i = 0; i < 4; i++)
      #pragma unroll
      for (int j = 0; j < 4; j++)
        acc[i][j] = (f32x4){0.f, 0.f, 0.f, 0.f};

    int ra0 = wv*16 + (l >> 2), ra1 = (wv+4)*16 + (l >> 2);
    int cc = (l & 3) * 8;
    const unsigned short* w1e = w1t + (size_t)e * DFF * DMODEL;
    const unsigned short* ga0 = xg + (size_t)(slotbase + ra0) * DMODEL + cc;
    const unsigned short* ga1 = xg + (size_t)(slotbase + ra1) * DMODEL + cc;
    const unsigned short* gb0 = w1e + (size_t)(n0 + ra0) * DMODEL + cc;
    const unsigned short* gb1 = w1e + (size_t)(n0 + ra1) * DMODEL + cc;
    char* lA0 = (char*)As + wv*1024;      char* lA1 = (char*)As + (wv+4)*1024;
    char* lB0 = (char*)Bs + wv*1024;      char* lB1 = (char*)Bs + (wv+4)*1024;

    for (int k0 = 0; k0 < DMODEL; k0 += 32) {
        gl_lds16(ga0 + k0, lA0);
        gl_lds16(ga1 + k0, lA1);
        gl_lds16(gb0 + k0, lB0);
        gl_lds16(gb1 + k0, lB1);
        __syncthreads();
        bf16x8 a[4], b[4];
        #pragma unroll
        for (int i = 0; i < 4; i++)
            a[i] = *(const bf16x8*)&As[(wm + i*16 + lrow)*32 + lkg*8];
        #pragma unroll
        for (int i = 0; i < 4; i++)
            b[i] = *(const bf16x8*)&Bs[(wn + i*16 + lrow)*32 + lkg*8];
        #pragma unroll
        for (int mi = 0; mi < 4; mi++)
          #pragma unroll
          for (int ni = 0; ni < 4; ni++)
            acc[mi][ni] = __builtin_amdgcn_mfma_f32_16x16x32_bf16(a[mi], b[ni], acc[mi][ni], 0, 0, 0);
        __syncthreads();
    }

    #pragma unroll
    for (int mi = 0; mi < 4; mi++) {
        #pragma unroll
        for (int ni = 0; ni < 4; ni++) {
            int n = n0 + wn + ni*16 + lrow;
            float bias = b1[e*DFF + n];
            #pragma unroll
            for (int r = 0; r < 4; r++) {
                int ml = wm + mi*16 + lkg*4 + r;
                if (mt*128 + ml < ne) {
                    float hv = acc[mi][ni][r] + bias;
                    hv = 0.5f * hv * (1.f + erff(hv * 0.70710678118f));
                    hbuf[(size_t)(slotbase + ml) * DFF + n] = f2bf(hv);
                }
            }
        }
    }
}

// ---------------- GEMM2: y[slot] = gate * (h @ w2t^T + b2) ----------------
__global__ __launch_bounds__(256) void k_ffn2(
    const unsigned short* __restrict__ hbuf, const unsigned short* __restrict__ w2t,
    const float* __restrict__ b2, const int* __restrict__ offsets,
    const float* __restrict__ slot_gate, float* __restrict__ y)
{
    int e = blockIdx.z;
    int base = offsets[e], ne = offsets[e+1] - base;
    int mt = blockIdx.y;
    if (mt * 128 >= ne) return;
    int n0 = blockIdx.x * 128;
    int slotbase = base + mt * 128;

    __shared__ unsigned short As[128*32];
    __shared__ unsigned short Bs[128*32];
    __shared__ float gat[128];

    int tid = threadIdx.x, l = tid & 63, wv = tid >> 6;
    if (tid < 128)
        gat[tid] = (mt*128 + tid < ne) ? slot_gate[slotbase + tid] : 0.f;

    int wm = (wv >> 1) * 64, wn = (wv & 1) * 64;
    int lrow = l & 15, lkg = l >> 4;

    f32x4 acc[4][4];
    #pragma unroll
    for (int i = 0; i < 4; i++)
      #pragma unroll
      for (int j = 0; j < 4; j++)
        acc[i][j] = (f32x4){0.f, 0.f, 0.f, 0.f};

    int ra0 = wv*16 + (l >> 2), ra1 = (wv+4)*16 + (l >> 2);
    int cc = (l & 3) * 8;
    const unsigned short* w2e = w2t + (size_t)e * DMODEL * DFF;
    const unsigned short* ga0 = hbuf + (size_t)(slotbase + ra0) * DFF + cc;
    const unsigned short* ga1 = hbuf + (size_t)(slotbase + ra1) * DFF + cc;
    const unsigned short* gb0 = w2e + (size_t)(n0 + ra0) * DFF + cc;
    const unsigned short* gb1 = w2e + (size_t)(n0 + ra1) * DFF + cc;
    char* lA0 = (char*)As + wv*1024;      char* lA1 = (char*)As + (wv+4)*1024;
    char* lB0 = (char*)Bs + wv*1024;      char* lB1 = (char*)Bs + (wv+4)*1024;

    for (int k0 = 0; k0 < DFF; k0 += 32) {
        gl_lds16(ga0 + k0, lA0);
        gl_lds16(ga1 + k0, lA1);
        gl_lds16(gb0 + k0, lB0);
        gl_lds16(gb1 + k0, lB1);
        __syncthreads();
        bf16x8 a[4], b[4];
        #pragma unroll
        for (int i = 0; i < 4; i++)
            a[i] = *(const bf16x8*)&As[(wm + i*16 + lrow)*32 + lkg*8];
        #pragma unroll
        for (int i = 0; i < 4; i++)
            b[i] = *(const bf16x8*)&Bs[(wn + i*16 + lrow)*32 + lkg*8];
        #pragma unroll
        for (int mi = 0; mi < 4; mi++)
          #pragma unroll
          for (int ni = 0; ni < 4; ni++)
            acc[mi][ni] = __builtin_amdgcn_mfma_f32_16x16x32_bf16(a[mi], b[ni], acc[mi][ni], 0, 0, 0);
        __syncthreads();
    }

    #pragma unroll
    for (int mi = 0; mi < 4; mi++) {
        #pragma unroll
        for (int ni = 0; ni < 4; ni++) {
            int n = n0 + wn + ni*16 + lrow;
            float bias = b2[e*DMODEL + n];
            #pragma unroll
            for (int r = 0; r < 4; r++) {
                int ml = wm + mi*16 + lkg*4 + r;
                if (mt*128 + ml < ne) {
                    y[(size_t)(slotbase + ml) * DMODEL + n] = gat[ml] * (acc[mi][ni][r] + bias);
                }
            }
        }
    }
}

// ---------------- combine: out[t] = y[slot0] + y[slot1] ----------------
__global__ __launch_bounds__(256) void k_combine(
    const float* __restrict__ y, const int* __restrict__ slot_of,
    float* __restrict__ out)
{
    int t = blockIdx.x, tid = threadIdx.x;
    int s0 = slot_of[t*2], s1 = slot_of[t*2+1];
    float4 a = ((const float4*)(y + (size_t)s0 * DMODEL))[tid];
    float4 b = ((const float4*)(y + (size_t)s1 * DMODEL))[tid];
    float4 o = {a.x+b.x, a.y+b.y, a.z+b.z, a.w+b.w};
    ((float4*)(out + (size_t)t * DMODEL))[tid] = o;
}

extern "C" void kernel_launch(void* const* d_in, const int* in_sizes, int n_in,
                              void* d_out, int out_size, void* d_ws, size_t ws_size,
                              hipStream_t stream) {
    const float* x  = (const float*)d_in[0];
    const float* gw = (const float*)d_in[1];
    const float* gb = (const float*)d_in[2];
    const float* w1 = (const float*)d_in[3];
    const float* b1 = (const float*)d_in[4];
    const float* w2 = (const float*)d_in[5];
    const float* b2 = (const float*)d_in[6];
    float* out = (float*)d_out;
    char* ws = (char*)d_ws;

    int*   counts     = (int*)(ws + 0);
    int*   counts2    = (int*)(ws + 128);
    int*   offsets    = (int*)(ws + 256);
    int*   topk_e     = (int*)(ws + 512);
    float* topk_g     = (float*)(ws + 33280);
    int*   slot_token = (int*)(ws + 66048);
    float* slot_gate  = (float*)(ws + 99328);
    int*   slot_of    = (int*)(ws + 132608);
    // xg (bf16, 17MB) and y (f32, 34MB) share the same region: disjoint lifetimes
    unsigned short* xg = (unsigned short*)(ws + 1048576);
    float*          y  = (float*)(ws + 1048576);
    unsigned short* hbuf = (unsigned short*)(ws + 35651584);   // 68.2 MB
    unsigned short* wt   = (unsigned short*)(ws + 104857600);  // 201.3 MB shared w1t/w2t

    hipMemsetAsync(ws, 0, 512, stream);

    k_gate<<<T_TOKENS/4, 256, 0, stream>>>(x, gw, gb, topk_e, topk_g, counts);
    k_scan<<<1, 64, 0, stream>>>(counts, offsets);
    k_assign<<<NSLOTS/256, 256, 0, stream>>>(topk_e, topk_g, offsets, counts2,
                                             slot_token, slot_gate, slot_of);
    k_xgather<<<NSLOTS*128/256, 256, 0, stream>>>(x, slot_token, xg);

    // w1 [E][1024][4096] -> wt [E][4096][1024]
    dim3 gt1(DFF/64, DMODEL/64, NEXP);
    k_wt<<<gt1, 256, 0, stream>>>(w1, wt, DMODEL, DFF);
    dim3 g1(DFF/128, 32, NEXP);
    k_ffn1<<<g1, 256, 0, stream>>>(xg, wt, b1, offsets, hbuf);

    // w2 [E][4096][1024] -> wt [E][1024][4096]
    dim3 gt2(DMODEL/64, DFF/64, NEXP);
    k_wt<<<gt2, 256, 0, stream>>>(w2, wt, DFF, DMODEL);
    dim3 g2(DMODEL/128, 32, NEXP);
    k_ffn2<<<g2, 256, 0, stream>>>(hbuf, wt, b2, offsets, slot_gate, y);

    k_combine<<<T_TOKENS, 256, 0, stream>>>(y, slot_of, out);
}

// Round 3
// 620.302 us; speedup vs baseline: 2.0139x; 1.4559x over previous
//
#include <hip/hip_runtime.h>
#include <hip/hip_bf16.h>
#include <math.h>

#define T_TOKENS 4096
#define DMODEL 1024
#define DFF 4096
#define NEXP 24
#define NSLOTS 8192
#define SLOTS_PAD 8320

typedef __attribute__((ext_vector_type(8))) short bf16x8;
typedef __attribute__((ext_vector_type(4))) float f32x4;
typedef __attribute__((ext_vector_type(8))) unsigned short us8;

static __device__ __forceinline__ unsigned short f2bf(float f) {
    union { float f; unsigned u; } v; v.f = f;
    unsigned r = v.u + 0x7fffu + ((v.u >> 16) & 1u);
    return (unsigned short)(r >> 16);
}

typedef const __attribute__((address_space(1))) void gvoid_t;
typedef __attribute__((address_space(3))) void lvoid_t;
static __device__ __forceinline__ void gl_lds16(const void* g, void* l) {
    __builtin_amdgcn_global_load_lds((gvoid_t*)g, (lvoid_t*)l, 16, 0, 0);
}

// ---------------- gating v2: block = 8 tokens x 32 lanes (lane = expert) --------
__global__ __launch_bounds__(256) void k_gate(
    const float* __restrict__ x, const float* __restrict__ gw,
    const float* __restrict__ gb, int* __restrict__ topk_e,
    float* __restrict__ topk_g, int* __restrict__ counts)
{
    __shared__ float xs[8][1024];
    __shared__ float sc[8][24];
    __shared__ int lcnt[24];
    int tid = threadIdx.x;
    int t0 = blockIdx.x * 8;
    #pragma unroll
    for (int i = 0; i < 8; i++) {
        int idx = tid + 256*i;                 // 2048 float4 = 8 rows x 1024
        int r = idx >> 8, c4 = (idx & 255) * 4;
        *(float4*)&xs[r][c4] = *(const float4*)(x + (size_t)(t0+r)*DMODEL + c4);
    }
    if (tid < 24) lcnt[tid] = 0;
    __syncthreads();

    int tok = tid >> 5, e = tid & 31;
    if (e < NEXP) {
        float s0=0.f, s1=0.f, s2=0.f, s3=0.f;
        #pragma unroll 4
        for (int d = 0; d < DMODEL; d += 4) {
            s0 += xs[tok][d]   * gw[(d  )*NEXP + e];
            s1 += xs[tok][d+1] * gw[(d+1)*NEXP + e];
            s2 += xs[tok][d+2] * gw[(d+2)*NEXP + e];
            s3 += xs[tok][d+3] * gw[(d+3)*NEXP + e];
        }
        sc[tok][e] = (s0+s1)+(s2+s3) + gb[e];
    }
    __syncthreads();

    if (tid < 8) {
        int t = t0 + tid;
        float v0=-1e30f, v1=-1e30f; int i0=0, i1=0;
        #pragma unroll
        for (int ee = 0; ee < NEXP; ee++) {
            float s = sc[tid][ee];
            if (s > v0) { v1=v0; i1=i0; v0=s; i0=ee; }
            else if (s > v1) { v1=s; i1=ee; }
        }
        float e1 = expf(v1 - v0);
        float g0 = 1.f/(1.f+e1), g1 = e1/(1.f+e1);
        topk_e[t*2]=i0; topk_e[t*2+1]=i1;
        topk_g[t*2]=g0; topk_g[t*2+1]=g1;
        atomicAdd(&lcnt[i0], 1); atomicAdd(&lcnt[i1], 1);
    }
    __syncthreads();
    if (tid < NEXP && lcnt[tid]) atomicAdd(&counts[tid], lcnt[tid]);
}

__global__ void k_scan(const int* __restrict__ counts, int* __restrict__ offsets) {
    if (threadIdx.x == 0) {
        int run = 0;
        for (int e = 0; e < NEXP; e++) { offsets[e] = run; run += counts[e]; }
        offsets[NEXP] = run;
    }
}

__global__ __launch_bounds__(256) void k_assign(
    const int* __restrict__ topk_e, const float* __restrict__ topk_g,
    const int* __restrict__ offsets, int* __restrict__ counts2,
    int* __restrict__ slot_token, float* __restrict__ slot_gate,
    int* __restrict__ slot_of)
{
    int idx = blockIdx.x * 256 + threadIdx.x;
    if (idx >= NSLOTS) return;
    int e = topk_e[idx];
    int pos = offsets[e] + atomicAdd(&counts2[e], 1);
    slot_token[pos] = idx >> 1;
    slot_gate[pos] = topk_g[idx];
    slot_of[idx] = pos;
}

// ---------------- gather x -> xg[slot][DMODEL] bf16 ----------------
__global__ __launch_bounds__(256) void k_xgather(
    const float* __restrict__ x, const int* __restrict__ slot_token,
    unsigned short* __restrict__ xg)
{
    int idx = blockIdx.x * 256 + threadIdx.x;
    int slot = idx >> 7, c8 = (idx & 127) * 8;
    int tok = slot_token[slot];
    const float4* p = (const float4*)(x + (size_t)tok * DMODEL + c8);
    float4 v0 = p[0], v1 = p[1];
    us8 o;
    o[0]=f2bf(v0.x); o[1]=f2bf(v0.y); o[2]=f2bf(v0.z); o[3]=f2bf(v0.w);
    o[4]=f2bf(v1.x); o[5]=f2bf(v1.y); o[6]=f2bf(v1.z); o[7]=f2bf(v1.w);
    *(us8*)(xg + (size_t)slot * DMODEL + c8) = o;
}

// ---------------- weight convert+transpose: [E][R][C] f32 -> [E][C][R] bf16 ----
__global__ __launch_bounds__(256) void k_wt(
    const float* __restrict__ in, unsigned short* __restrict__ out, int R, int C)
{
    __shared__ unsigned short Lt[64][66];
    int e = blockIdx.z;
    int c0 = blockIdx.x * 64, r0 = blockIdx.y * 64;
    const float* ip = in + (size_t)e * R * C;
    unsigned short* op = out + (size_t)e * R * C;
    int tid = threadIdx.x;
    #pragma unroll
    for (int i = 0; i < 4; i++) {
        int idx = tid + 256*i;
        int r = idx >> 4, c4 = (idx & 15) * 4;
        float4 v = *(const float4*)(ip + (size_t)(r0+r)*C + c0 + c4);
        unsigned lo = (unsigned)f2bf(v.x) | ((unsigned)f2bf(v.y) << 16);
        unsigned hi = (unsigned)f2bf(v.z) | ((unsigned)f2bf(v.w) << 16);
        *(unsigned*)&Lt[r][c4]   = lo;
        *(unsigned*)&Lt[r][c4+2] = hi;
    }
    __syncthreads();
    #pragma unroll
    for (int j = 0; j < 2; j++) {
        int idx = tid + 256*j;
        int c = idx >> 3, r8 = (idx & 7) * 8;
        us8 o;
        #pragma unroll
        for (int k = 0; k < 8; k++) o[k] = Lt[r8+k][c];
        *(us8*)(op + (size_t)(c0+c)*R + r0 + r8) = o;
    }
}

// ---------------- GEMM1: h = gelu(xg @ w1t^T + b1), m97 structure ----------------
__global__ __launch_bounds__(256) void k_ffn1(
    const unsigned short* __restrict__ xg, const unsigned short* __restrict__ w1t,
    const float* __restrict__ b1, const int* __restrict__ offsets,
    unsigned short* __restrict__ hbuf)
{
    int e = blockIdx.z;
    int base = offsets[e], ne = offsets[e+1] - base;
    int mt = blockIdx.y;
    if (mt * 128 >= ne) return;
    int n0 = blockIdx.x * 128;
    int slotbase = base + mt * 128;

    __shared__ unsigned short As[128*32];
    __shared__ unsigned short Bs[128*32];

    int tid = threadIdx.x, l = tid & 63, wv = tid >> 6;
    int wm = (wv >> 1) * 64, wn = (wv & 1) * 64;
    int lrow = l & 15, lkg = l >> 4;

    f32x4 acc[4][4];
    #pragma unroll
    for (int i = 0; i < 4; i++)
      #pragma unroll
      for (int j = 0; j < 4; j++)
        acc[i][j] = (f32x4){0.f, 0.f, 0.f, 0.f};

    int ra0 = wv*16 + (l >> 2), ra1 = (wv+4)*16 + (l >> 2);
    int cc = (l & 3) * 8;
    const unsigned short* w1e = w1t + (size_t)e * DFF * DMODEL;
    const unsigned short* ga0 = xg + (size_t)(slotbase + ra0) * DMODEL + cc;
    const unsigned short* ga1 = xg + (size_t)(slotbase + ra1) * DMODEL + cc;
    const unsigned short* gb0 = w1e + (size_t)(n0 + ra0) * DMODEL + cc;
    const unsigned short* gb1 = w1e + (size_t)(n0 + ra1) * DMODEL + cc;
    char* lA0 = (char*)As + wv*1024;      char* lA1 = (char*)As + (wv+4)*1024;
    char* lB0 = (char*)Bs + wv*1024;      char* lB1 = (char*)Bs + (wv+4)*1024;

    for (int k0 = 0; k0 < DMODEL; k0 += 32) {
        gl_lds16(ga0 + k0, lA0);
        gl_lds16(ga1 + k0, lA1);
        gl_lds16(gb0 + k0, lB0);
        gl_lds16(gb1 + k0, lB1);
        __syncthreads();
        bf16x8 a[4], b[4];
        #pragma unroll
        for (int i = 0; i < 4; i++)
            a[i] = *(const bf16x8*)&As[(wm + i*16 + lrow)*32 + lkg*8];
        #pragma unroll
        for (int i = 0; i < 4; i++)
            b[i] = *(const bf16x8*)&Bs[(wn + i*16 + lrow)*32 + lkg*8];
        #pragma unroll
        for (int mi = 0; mi < 4; mi++)
          #pragma unroll
          for (int ni = 0; ni < 4; ni++)
            acc[mi][ni] = __builtin_amdgcn_mfma_f32_16x16x32_bf16(a[mi], b[ni], acc[mi][ni], 0, 0, 0);
        __syncthreads();
    }

    #pragma unroll
    for (int mi = 0; mi < 4; mi++) {
        #pragma unroll
        for (int ni = 0; ni < 4; ni++) {
            int n = n0 + wn + ni*16 + lrow;
            float bias = b1[e*DFF + n];
            #pragma unroll
            for (int r = 0; r < 4; r++) {
                int ml = wm + mi*16 + lkg*4 + r;
                if (mt*128 + ml < ne) {
                    float hv = acc[mi][ni][r] + bias;
                    hv = 0.5f * hv * (1.f + erff(hv * 0.70710678118f));
                    hbuf[(size_t)(slotbase + ml) * DFF + n] = f2bf(hv);
                }
            }
        }
    }
}

// ---------------- GEMM2: y[slot] = gate * (h @ w2t^T + b2) ----------------
__global__ __launch_bounds__(256) void k_ffn2(
    const unsigned short* __restrict__ hbuf, const unsigned short* __restrict__ w2t,
    const float* __restrict__ b2, const int* __restrict__ offsets,
    const float* __restrict__ slot_gate, float* __restrict__ y)
{
    int e = blockIdx.z;
    int base = offsets[e], ne = offsets[e+1] - base;
    int mt = blockIdx.y;
    if (mt * 128 >= ne) return;
    int n0 = blockIdx.x * 128;
    int slotbase = base + mt * 128;

    __shared__ unsigned short As[128*32];
    __shared__ unsigned short Bs[128*32];
    __shared__ float gat[128];

    int tid = threadIdx.x, l = tid & 63, wv = tid >> 6;
    if (tid < 128)
        gat[tid] = (mt*128 + tid < ne) ? slot_gate[slotbase + tid] : 0.f;

    int wm = (wv >> 1) * 64, wn = (wv & 1) * 64;
    int lrow = l & 15, lkg = l >> 4;

    f32x4 acc[4][4];
    #pragma unroll
    for (int i = 0; i < 4; i++)
      #pragma unroll
      for (int j = 0; j < 4; j++)
        acc[i][j] = (f32x4){0.f, 0.f, 0.f, 0.f};

    int ra0 = wv*16 + (l >> 2), ra1 = (wv+4)*16 + (l >> 2);
    int cc = (l & 3) * 8;
    const unsigned short* w2e = w2t + (size_t)e * DMODEL * DFF;
    const unsigned short* ga0 = hbuf + (size_t)(slotbase + ra0) * DFF + cc;
    const unsigned short* ga1 = hbuf + (size_t)(slotbase + ra1) * DFF + cc;
    const unsigned short* gb0 = w2e + (size_t)(n0 + ra0) * DFF + cc;
    const unsigned short* gb1 = w2e + (size_t)(n0 + ra1) * DFF + cc;
    char* lA0 = (char*)As + wv*1024;      char* lA1 = (char*)As + (wv+4)*1024;
    char* lB0 = (char*)Bs + wv*1024;      char* lB1 = (char*)Bs + (wv+4)*1024;

    for (int k0 = 0; k0 < DFF; k0 += 32) {
        gl_lds16(ga0 + k0, lA0);
        gl_lds16(ga1 + k0, lA1);
        gl_lds16(gb0 + k0, lB0);
        gl_lds16(gb1 + k0, lB1);
        __syncthreads();
        bf16x8 a[4], b[4];
        #pragma unroll
        for (int i = 0; i < 4; i++)
            a[i] = *(const bf16x8*)&As[(wm + i*16 + lrow)*32 + lkg*8];
        #pragma unroll
        for (int i = 0; i < 4; i++)
            b[i] = *(const bf16x8*)&Bs[(wn + i*16 + lrow)*32 + lkg*8];
        #pragma unroll
        for (int mi = 0; mi < 4; mi++)
          #pragma unroll
          for (int ni = 0; ni < 4; ni++)
            acc[mi][ni] = __builtin_amdgcn_mfma_f32_16x16x32_bf16(a[mi], b[ni], acc[mi][ni], 0, 0, 0);
        __syncthreads();
    }

    #pragma unroll
    for (int mi = 0; mi < 4; mi++) {
        #pragma unroll
        for (int ni = 0; ni < 4; ni++) {
            int n = n0 + wn + ni*16 + lrow;
            float bias = b2[e*DMODEL + n];
            #pragma unroll
            for (int r = 0; r < 4; r++) {
                int ml = wm + mi*16 + lkg*4 + r;
                if (mt*128 + ml < ne) {
                    y[(size_t)(slotbase + ml) * DMODEL + n] = gat[ml] * (acc[mi][ni][r] + bias);
                }
            }
        }
    }
}

// ---------------- combine: out[t] = y[slot0] + y[slot1] ----------------
__global__ __launch_bounds__(256) void k_combine(
    const float* __restrict__ y, const int* __restrict__ slot_of,
    float* __restrict__ out)
{
    int t = blockIdx.x, tid = threadIdx.x;
    int s0 = slot_of[t*2], s1 = slot_of[t*2+1];
    float4 a = ((const float4*)(y + (size_t)s0 * DMODEL))[tid];
    float4 b = ((const float4*)(y + (size_t)s1 * DMODEL))[tid];
    float4 o = {a.x+b.x, a.y+b.y, a.z+b.z, a.w+b.w};
    ((float4*)(out + (size_t)t * DMODEL))[tid] = o;
}

extern "C" void kernel_launch(void* const* d_in, const int* in_sizes, int n_in,
                              void* d_out, int out_size, void* d_ws, size_t ws_size,
                              hipStream_t stream) {
    const float* x  = (const float*)d_in[0];
    const float* gw = (const float*)d_in[1];
    const float* gb = (const float*)d_in[2];
    const float* w1 = (const float*)d_in[3];
    const float* b1 = (const float*)d_in[4];
    const float* w2 = (const float*)d_in[5];
    const float* b2 = (const float*)d_in[6];
    float* out = (float*)d_out;
    char* ws = (char*)d_ws;

    int*   counts     = (int*)(ws + 0);
    int*   counts2    = (int*)(ws + 128);
    int*   offsets    = (int*)(ws + 256);
    int*   topk_e     = (int*)(ws + 512);
    float* topk_g     = (float*)(ws + 33280);
    int*   slot_token = (int*)(ws + 66048);
    float* slot_gate  = (float*)(ws + 99328);
    int*   slot_of    = (int*)(ws + 132608);
    unsigned short* xg = (unsigned short*)(ws + 1048576);
    float*          y  = (float*)(ws + 1048576);
    unsigned short* hbuf = (unsigned short*)(ws + 35651584);
    unsigned short* wt   = (unsigned short*)(ws + 104857600);

    hipMemsetAsync(ws, 0, 512, stream);

    k_gate<<<T_TOKENS/8, 256, 0, stream>>>(x, gw, gb, topk_e, topk_g, counts);
    k_scan<<<1, 64, 0, stream>>>(counts, offsets);
    k_assign<<<NSLOTS/256, 256, 0, stream>>>(topk_e, topk_g, offsets, counts2,
                                             slot_token, slot_gate, slot_of);
    k_xgather<<<NSLOTS*128/256, 256, 0, stream>>>(x, slot_token, xg);

    dim3 gt1(DFF/64, DMODEL/64, NEXP);
    k_wt<<<gt1, 256, 0, stream>>>(w1, wt, DMODEL, DFF);
    dim3 g1(DFF/128, 32, NEXP);
    k_ffn1<<<g1, 256, 0, stream>>>(xg, wt, b1, offsets, hbuf);

    dim3 gt2(DMODEL/64, DFF/64, NEXP);
    k_wt<<<gt2, 256, 0, stream>>>(w2, wt, DFF, DMODEL);
    dim3 g2(DMODEL/128, 32, NEXP);
    k_ffn2<<<g2, 256, 0, stream>>>(hbuf, wt, b2, offsets, slot_gate, y);

    k_combine<<<T_TOKENS, 256, 0, stream>>>(y, slot_of, out);
}